// Round 2
// baseline (379.984 us; speedup 1.0000x reference)
//
#include <hip/hip_runtime.h>

// DPP quad_perm controls: lane <- lane^1 / lane^2 / lane^3 within each quad
#define DPP_XOR1 0xB1   // [1,0,3,2]
#define DPP_XOR2 0x4E   // [2,3,0,1]
#define DPP_XOR3 0x1B   // [3,2,1,0]

// Measurement round: repeat the steady-state row computation REP times inside
// the dispatch so the kernel exceeds the harness fill kernels (~95us) and
// shows up in rocprof top-k with full counters. A memory clobber at each rep
// boundary defeats load-CSE across reps (rule #17) without perturbing
// intra-rep scheduling. Output is overwritten with identical values each rep.
#define REP 8

template <int CTRL>
__device__ __forceinline__ float dppf(float x) {
  return __int_as_float(__builtin_amdgcn_update_dpp(
      0, __float_as_int(x), CTRL, 0xF, 0xF, true));
}

__device__ __forceinline__ float fast_tanh(float x) {
  // tanh(x) = 1 - 2/(e^{2x}+1)
  float e = __expf(2.0f * x);
  float r = __builtin_amdgcn_rcpf(e + 1.0f);
  return fmaf(-2.0f, r, 1.0f);
}

// B=16384, D=2472, N=50, H=4. 4 lanes per row, 64 rows/block, 256 blocks.
__global__ __launch_bounds__(256) void rec_policy_kernel(
    const float* __restrict__ x,
    const float* __restrict__ Wcf1, const float* __restrict__ bcf1,
    const float* __restrict__ Wihu, const float* __restrict__ bihu,
    const float* __restrict__ Whhu, const float* __restrict__ bhhu,
    const float* __restrict__ Wfc1, const float* __restrict__ bfc1,
    const float* __restrict__ Wfc2, const float* __restrict__ bfc2,
    const float* __restrict__ Wihd, const float* __restrict__ bihd,
    const float* __restrict__ Whhd, const float* __restrict__ bhhd,
    const float* __restrict__ Wout, const float* __restrict__ bout,
    float* __restrict__ out)
{
  const int tid = threadIdx.x;
  const int l   = tid & 3;
  const int b   = blockIdx.x * 64 + (tid >> 2);
  const float* __restrict__ xr = x + (size_t)b * 2472;

  // ---------------- weight prep (hoisted out of the rep loop) ----------------
  float wihu[4][4];
  #pragma unroll
  for (int m = 0; m < 4; ++m) {
    #pragma unroll
    for (int k = 0; k < 4; ++k) wihu[m][k] = Wihu[m * 4 + k];
  }
  float wck[4][4];   // folded Wc = W_ih_up @ W_cf1; wck[m][j] = Wc[m][l + 4j]
  #pragma unroll
  for (int m = 0; m < 4; ++m) {
    #pragma unroll
    for (int j = 0; j < 4; ++j) {
      const int c = l + 4 * j;
      wck[m][j] = wihu[m][0] * Wcf1[c]      + wihu[m][1] * Wcf1[16 + c]
                + wihu[m][2] * Wcf1[32 + c] + wihu[m][3] * Wcf1[48 + c];
    }
  }
  float btot = bihu[l] + bhhu[l]
             + Wihu[l * 4 + 0] * bcf1[0] + Wihu[l * 4 + 1] * bcf1[1]
             + Wihu[l * 4 + 2] * bcf1[2] + Wihu[l * 4 + 3] * bcf1[3];
  float whhp[4];
  #pragma unroll
  for (int j = 0; j < 4; ++j) whhp[j] = Whhu[l * 4 + (l ^ j)];

  float wfc1o[7], wfc1h[4], wfc2p[4];
  #pragma unroll
  for (int k = 0; k < 7; ++k) wfc1o[k] = Wfc1[l * 11 + k];
  #pragma unroll
  for (int j = 0; j < 4; ++j) wfc1h[j] = Wfc1[l * 11 + 7 + (l ^ j)];
  #pragma unroll
  for (int j = 0; j < 4; ++j) wfc2p[j] = Wfc2[l * 4 + (l ^ j)];
  const float bfc1l = bfc1[l];
  const float bfc2l = bfc2[l];

  float wid[4], whd[4], wo[4];
  #pragma unroll
  for (int j = 0; j < 4; ++j) {
    wid[j] = Wihd[l * 4 + (l ^ j)];
    whd[j] = Whhd[l * 4 + (l ^ j)];
    wo[j]  = Wout[l ^ j];
  }
  const float bdn = bihd[l] + bhhd[l];
  const float wo4 = Wout[4];
  const float bo  = bout[0];

  const bool s1  = (l & 1) != 0;
  const bool s2b = (l & 2) != 0;

  #pragma unroll 1
  for (int rep = 0; rep < REP; ++rep) {
    asm volatile("" ::: "memory");   // force re-loads each rep; no intra-rep effect

    // ---------------- up scan: i = 49 .. 0 ----------------
    float h = 0.0f;
    float hup[7];

    #pragma unroll
    for (int i = 49; i >= 0; --i) {
      const float* pA = xr + 7 + 50 * i + l;
      const float* pB = xr + 407 + 8 * i + l;
      float v0 = pA[0];
      float v1 = pA[4];
      float v2 = pB[0];
      float v3 = pB[4];

      float p0 = fmaf(wck[0][0], v0, fmaf(wck[0][1], v1, fmaf(wck[0][2], v2, wck[0][3] * v3)));
      float p1 = fmaf(wck[1][0], v0, fmaf(wck[1][1], v1, fmaf(wck[1][2], v2, wck[1][3] * v3)));
      float p2 = fmaf(wck[2][0], v0, fmaf(wck[2][1], v1, fmaf(wck[2][2], v2, wck[2][3] * v3)));
      float p3 = fmaf(wck[3][0], v0, fmaf(wck[3][1], v1, fmaf(wck[3][2], v2, wck[3][3] * v3)));

      p0 += dppf<DPP_XOR1>(p0); p1 += dppf<DPP_XOR1>(p1);
      p2 += dppf<DPP_XOR1>(p2); p3 += dppf<DPP_XOR1>(p3);
      p0 += dppf<DPP_XOR2>(p0); p1 += dppf<DPP_XOR2>(p1);
      p2 += dppf<DPP_XOR2>(p2); p3 += dppf<DPP_XOR2>(p3);

      float sel = s2b ? (s1 ? p3 : p2) : (s1 ? p1 : p0);

      float g1 = dppf<DPP_XOR1>(h);
      float g2 = dppf<DPP_XOR2>(h);
      float g3 = dppf<DPP_XOR3>(h);
      float s = sel + btot;
      s = fmaf(whhp[0], h,  s);
      s = fmaf(whhp[1], g1, s);
      s = fmaf(whhp[2], g2, s);
      s = fmaf(whhp[3], g3, s);
      h = fast_tanh(s);

      if (i < 7) hup[i] = h;
    }

    // ---------------- fc stage ----------------
    float pre1 = bfc1l;
    #pragma unroll
    for (int k = 0; k < 7; ++k) pre1 = fmaf(wfc1o[k], xr[k], pre1);
    {
      float g1 = dppf<DPP_XOR1>(h);
      float g2 = dppf<DPP_XOR2>(h);
      float g3 = dppf<DPP_XOR3>(h);
      pre1 = fmaf(wfc1h[0], h,  pre1);
      pre1 = fmaf(wfc1h[1], g1, pre1);
      pre1 = fmaf(wfc1h[2], g2, pre1);
      pre1 = fmaf(wfc1h[3], g3, pre1);
    }
    float t1 = fast_tanh(pre1);
    float acc2 = bfc2l;
    {
      float g1 = dppf<DPP_XOR1>(t1);
      float g2 = dppf<DPP_XOR2>(t1);
      float g3 = dppf<DPP_XOR3>(t1);
      acc2 = fmaf(wfc2p[0], t1, acc2);
      acc2 = fmaf(wfc2p[1], g1, acc2);
      acc2 = fmaf(wfc2p[2], g2, acc2);
      acc2 = fmaf(wfc2p[3], g3, acc2);
    }
    h = fast_tanh(acc2);

    // ---------------- down scan: t = 0..6 ----------------
    #pragma unroll
    for (int t = 0; t < 7; ++t) {
      float g1 = dppf<DPP_XOR1>(h);
      float g2 = dppf<DPP_XOR2>(h);
      float g3 = dppf<DPP_XOR3>(h);
      float act = fmaf(wo4, xr[7 + t], bo);
      act = fmaf(wo[0], h,  act);
      act = fmaf(wo[1], g1, act);
      act = fmaf(wo[2], g2, act);
      act = fmaf(wo[3], g3, act);
      if (l == 0) out[(size_t)b * 7 + t] = act;

      float hu = hup[t];
      float u1 = dppf<DPP_XOR1>(hu);
      float u2 = dppf<DPP_XOR2>(hu);
      float u3 = dppf<DPP_XOR3>(hu);
      float s = bdn;
      s = fmaf(wid[0], hu, s);
      s = fmaf(wid[1], u1, s);
      s = fmaf(wid[2], u2, s);
      s = fmaf(wid[3], u3, s);
      s = fmaf(whd[0], h,  s);
      s = fmaf(whd[1], g1, s);
      s = fmaf(whd[2], g2, s);
      s = fmaf(whd[3], g3, s);
      h = fast_tanh(s);
    }
  }
}

extern "C" void kernel_launch(void* const* d_in, const int* in_sizes, int n_in,
                              void* d_out, int out_size, void* d_ws, size_t ws_size,
                              hipStream_t stream) {
  (void)in_sizes; (void)n_in; (void)d_ws; (void)ws_size; (void)out_size;
  rec_policy_kernel<<<dim3(256), dim3(256), 0, stream>>>(
      (const float*)d_in[0],
      (const float*)d_in[1],  (const float*)d_in[2],
      (const float*)d_in[3],  (const float*)d_in[4],
      (const float*)d_in[5],  (const float*)d_in[6],
      (const float*)d_in[7],  (const float*)d_in[8],
      (const float*)d_in[9],  (const float*)d_in[10],
      (const float*)d_in[11], (const float*)d_in[12],
      (const float*)d_in[13], (const float*)d_in[14],
      (const float*)d_in[15], (const float*)d_in[16],
      (float*)d_out);
}